// Round 3
// baseline (584.381 us; speedup 1.0000x reference)
//
#include <hip/hip_runtime.h>
#include <hip/hip_bf16.h>
#include <cstdint>
#include <cstddef>

// ArcFace FC: out[i][j] = S * (j==label[i] ? phi(cos_ij) : cos_ij)
// cos = normalize(x) @ normalize(W)^T,  B=512, D=512, C=100000
//
// v4: barrier-free register-direct GEMM. The mfma_f32_16x16x32_bf16 fragment
// layout (lane l holds [row/col = l&15][k = (l>>4)*8 + j], 16B/32B contiguous)
// lets each wave load A (bf16) and W (fp32, cvt in-reg) straight from global
// memory into MFMA operand registers: no LDS, no __syncthreads in the K-loop,
// waves free-run and hide each other's latency (R2 showed barrier-locked
// staging was 100% latency-bound: Mfma 11%, VALU 18%, HBM 21%).
// W is L2/L3-resident (R2 FETCH=112MB) so the 16-lines-per-instr access
// pattern is cache-absorbed; every line is fully consumed over the k-loop.
// 1/||w|| accumulates per-lane during loads; B-frag col == C/D col == l&15,
// so the epilogue scale is lane-local (no broadcast).

#define SSCALE 30.0f
#define COSM_  0.8775825618903728f
#define SINM_  0.4794255386042030f
#define TH_    (-0.8775825618903728f)
#define MM_    0.2397127693021015f
#define EPS_   1e-12f

typedef unsigned short ushort_t;
typedef __attribute__((ext_vector_type(8))) short bf16x8;
typedef __attribute__((ext_vector_type(4))) float f32x4;

__device__ inline ushort_t f2bf(float f) {
    union { float f; unsigned u; } x; x.f = f;
    unsigned r = (x.u + 0x7fffu + ((x.u >> 16) & 1u)) >> 16;
    return (ushort_t)r;
}

__device__ inline ushort_t bfbits(float f) {
    union { __hip_bfloat16 h; ushort_t u; } c;
    c.h = __float2bfloat16(f);
    return c.u;
}

__device__ inline bf16x8 cvt8(float4 a, float4 b) {
    bf16x8 r;
    r[0] = (short)bfbits(a.x); r[1] = (short)bfbits(a.y);
    r[2] = (short)bfbits(a.z); r[3] = (short)bfbits(a.w);
    r[4] = (short)bfbits(b.x); r[5] = (short)bfbits(b.y);
    r[6] = (short)bfbits(b.z); r[7] = (short)bfbits(b.w);
    return r;
}

// ---------------- normalize x rows (D=512) fp32 -> bf16 (tiny: 512 rows) ----
__global__ __launch_bounds__(256) void norm_rows_bf16(const float* __restrict__ src,
                                                      ushort_t* __restrict__ dst,
                                                      int nrows) {
    int row = blockIdx.x * 4 + (threadIdx.x >> 6);
    if (row >= nrows) return;
    int lane = threadIdx.x & 63;
    const float* s = src + (size_t)row * 512;
    float4 a = ((const float4*)s)[lane];
    float4 b = ((const float4*)s)[lane + 64];
    float ss = a.x*a.x + a.y*a.y + a.z*a.z + a.w*a.w
             + b.x*b.x + b.y*b.y + b.z*b.z + b.w*b.w;
    #pragma unroll
    for (int off = 32; off > 0; off >>= 1) ss += __shfl_down(ss, off, 64);
    ss = __shfl(ss, 0, 64);
    float inv = 1.0f / fmaxf(sqrtf(ss), EPS_);
    ushort_t* d = dst + (size_t)row * 512;
    union { ushort_t u[4]; uint2 v; } oa, ob;
    oa.u[0] = f2bf(a.x * inv); oa.u[1] = f2bf(a.y * inv);
    oa.u[2] = f2bf(a.z * inv); oa.u[3] = f2bf(a.w * inv);
    ob.u[0] = f2bf(b.x * inv); ob.u[1] = f2bf(b.y * inv);
    ob.u[2] = f2bf(b.z * inv); ob.u[3] = f2bf(b.w * inv);
    ((uint2*)d)[lane]      = oa.v;
    ((uint2*)d)[lane + 64] = ob.v;
}

// ---------------- barrier-free register-direct fused GEMM -------------------
// out[M,N] = S * A[M,K] @ (W[N,K] * invw[N])^T,  A already normalized bf16.
// Block tile 128x128, 4 waves each 64x64 via 4x4 of mfma_f32_16x16x32_bf16.
// Lane (q = lane>>4, s = lane&15):
//   a-frag[msub]: A[bm*128 + (wave>>1)*64 + msub*16 + s][k0 + q*8 .. +8)
//   b-frag[nsub]: W[bn*128 + (wave&1)*64 + nsub*16 + s][k0 + q*8 .. +8)
//   C/D:          row = msub*16 + q*4 + reg, col = nsub*16 + s
__global__ __launch_bounds__(256) void gemm_fused(const ushort_t* __restrict__ A,
                                                  const float* __restrict__ W,
                                                  float* __restrict__ out,
                                                  int M, int N, int K) {
    int tid  = threadIdx.x;
    int wave = tid >> 6, lane = tid & 63;
    int q = lane >> 4, s = lane & 15;

    // XCD-chunked bijective remap (kept from v3: FETCH 401->112 MB)
    int nwg = gridDim.x;
    int nbm = M >> 7;
    int qq = nwg >> 3, rr = nwg & 7;
    int xcd = blockIdx.x & 7, pos = blockIdx.x >> 3;
    int logical = (xcd < rr ? xcd * (qq + 1) : rr * (qq + 1) + (xcd - rr) * qq) + pos;
    int bm = logical % nbm;
    int bn = logical / nbm;

    f32x4 acc[4][4];
    #pragma unroll
    for (int m = 0; m < 4; m++)
        #pragma unroll
        for (int n = 0; n < 4; n++)
            acc[m][n] = (f32x4){0.f, 0.f, 0.f, 0.f};

    // per-lane operand row pointers
    const ushort_t* pa[4];
    #pragma unroll
    for (int m = 0; m < 4; m++) {
        int ar = bm * 128 + (wave >> 1) * 64 + m * 16 + s;
        pa[m] = A + (size_t)ar * K + q * 8;
    }
    const float* pw[4];
    #pragma unroll
    for (int n = 0; n < 4; n++) {
        int br = bn * 128 + (wave & 1) * 64 + n * 16 + s;
        if (br > N - 1) br = N - 1;
        pw[n] = W + (size_t)br * K + q * 8;
    }

    float ss0 = 0.f, ss1 = 0.f, ss2 = 0.f, ss3 = 0.f;

    for (int k0 = 0; k0 < K; k0 += 32) {
        bf16x8 a[4];
        #pragma unroll
        for (int m = 0; m < 4; m++)
            a[m] = *(const bf16x8*)(pa[m] + k0);

        bf16x8 b[4];
        {
            float4 w0, w1;
            w0 = *(const float4*)(pw[0] + k0); w1 = *(const float4*)(pw[0] + k0 + 4);
            ss0 += w0.x*w0.x + w0.y*w0.y + w0.z*w0.z + w0.w*w0.w
                 + w1.x*w1.x + w1.y*w1.y + w1.z*w1.z + w1.w*w1.w;
            b[0] = cvt8(w0, w1);
            w0 = *(const float4*)(pw[1] + k0); w1 = *(const float4*)(pw[1] + k0 + 4);
            ss1 += w0.x*w0.x + w0.y*w0.y + w0.z*w0.z + w0.w*w0.w
                 + w1.x*w1.x + w1.y*w1.y + w1.z*w1.z + w1.w*w1.w;
            b[1] = cvt8(w0, w1);
            w0 = *(const float4*)(pw[2] + k0); w1 = *(const float4*)(pw[2] + k0 + 4);
            ss2 += w0.x*w0.x + w0.y*w0.y + w0.z*w0.z + w0.w*w0.w
                 + w1.x*w1.x + w1.y*w1.y + w1.z*w1.z + w1.w*w1.w;
            b[2] = cvt8(w0, w1);
            w0 = *(const float4*)(pw[3] + k0); w1 = *(const float4*)(pw[3] + k0 + 4);
            ss3 += w0.x*w0.x + w0.y*w0.y + w0.z*w0.z + w0.w*w0.w
                 + w1.x*w1.x + w1.y*w1.y + w1.z*w1.z + w1.w*w1.w;
            b[3] = cvt8(w0, w1);
        }

        #pragma unroll
        for (int m = 0; m < 4; m++)
            #pragma unroll
            for (int n = 0; n < 4; n++)
                acc[m][n] = __builtin_amdgcn_mfma_f32_16x16x32_bf16(
                    a[m], b[n], acc[m][n], 0, 0, 0);
    }

    // finish 1/||w||: lane covers k-quarter q of its row; sum across q (lane
    // bits 4,5), leaving the full row-norm in every lane of the group.
    float inv[4];
    {
        float t;
        t = ss0; t += __shfl_xor(t, 16, 64); t += __shfl_xor(t, 32, 64);
        inv[0] = SSCALE / fmaxf(sqrtf(t), EPS_);
        t = ss1; t += __shfl_xor(t, 16, 64); t += __shfl_xor(t, 32, 64);
        inv[1] = SSCALE / fmaxf(sqrtf(t), EPS_);
        t = ss2; t += __shfl_xor(t, 16, 64); t += __shfl_xor(t, 32, 64);
        inv[2] = SSCALE / fmaxf(sqrtf(t), EPS_);
        t = ss3; t += __shfl_xor(t, 16, 64); t += __shfl_xor(t, 32, 64);
        inv[3] = SSCALE / fmaxf(sqrtf(t), EPS_);
    }

    // epilogue: C/D col = s (same lane mapping as b-frag -> inv is lane-local)
    int row0 = bm * 128 + (wave >> 1) * 64 + q * 4;
    int col0 = bn * 128 + (wave & 1) * 64 + s;
    #pragma unroll
    for (int n = 0; n < 4; n++) {
        int c = col0 + n * 16;
        if (c < N) {
            #pragma unroll
            for (int m = 0; m < 4; m++) {
                #pragma unroll
                for (int r = 0; r < 4; r++) {
                    int row = row0 + m * 16 + r;
                    __builtin_nontemporal_store(acc[m][n][r] * inv[n],
                                                &out[(size_t)row * N + c]);
                }
            }
        }
    }
}

// ---------------- fixup: apply arcface margin at (i, label[i]) ---------------
__global__ void fixup_kernel(const int* __restrict__ label, float* __restrict__ out,
                             int Bsz, int C) {
    int i = blockIdx.x * blockDim.x + threadIdx.x;
    if (i >= Bsz) return;
    int j = label[i];
    size_t idx = (size_t)i * C + j;
    float cosv = out[idx] * (1.0f / SSCALE);
    float sinv = sqrtf(fmaxf(0.f, 1.f - cosv * cosv));
    float phi = cosv * COSM_ - sinv * SINM_;
    if (!(cosv > TH_)) phi = cosv - MM_;
    out[idx] = phi * SSCALE;
}

// ---------------- fallback path (workspace too small / odd shapes) ----------
__global__ __launch_bounds__(256) void rownorm_inv(const float* __restrict__ in,
                                                   float* __restrict__ invn, int nrows) {
    int row = blockIdx.x * 4 + (threadIdx.x >> 6);
    if (row >= nrows) return;
    int lane = threadIdx.x & 63;
    const float4* p = (const float4*)(in + (size_t)row * 512);
    float4 a = p[lane];
    float4 b = p[lane + 64];
    float ss = a.x*a.x + a.y*a.y + a.z*a.z + a.w*a.w
             + b.x*b.x + b.y*b.y + b.z*b.z + b.w*b.w;
    #pragma unroll
    for (int off = 32; off > 0; off >>= 1) ss += __shfl_down(ss, off, 64);
    if (lane == 0) invn[row] = 1.0f / fmaxf(sqrtf(ss), EPS_);
}

__global__ __launch_bounds__(256) void naive_gemm(const float* __restrict__ x,
                                                  const float* __restrict__ w,
                                                  const float* __restrict__ invx,
                                                  const float* __restrict__ invw,
                                                  float* __restrict__ out, int Bsz, int C) {
    __shared__ float xs[512];
    int i = blockIdx.y;
    int j = blockIdx.x * 256 + threadIdx.x;
    for (int k = threadIdx.x; k < 512; k += 256) xs[k] = x[(size_t)i * 512 + k];
    __syncthreads();
    if (j >= C) return;
    const float* wr = w + (size_t)j * 512;
    float acc = 0.f;
    for (int k = 0; k < 512; k++) acc += xs[k] * wr[k];
    out[(size_t)i * C + j] = acc * invx[i] * invw[j] * SSCALE;
}

extern "C" void kernel_launch(void* const* d_in, const int* in_sizes, int n_in,
                              void* d_out, int out_size, void* d_ws, size_t ws_size,
                              hipStream_t stream) {
    const float* x = (const float*)d_in[0];
    const float* w = (const float*)d_in[1];
    const int* label = (const int*)d_in[2];
    float* out = (float*)d_out;

    const int Bsz = in_sizes[2];            // 512
    const int D   = 512;
    const int C   = in_sizes[1] / D;        // 100000

    size_t need = (size_t)Bsz * D * sizeof(ushort_t);   // xn only: 512 KB
    if (ws_size >= need && (Bsz % 128) == 0) {
        ushort_t* xn = (ushort_t*)d_ws;
        norm_rows_bf16<<<(Bsz + 3) / 4, 256, 0, stream>>>(x, xn, Bsz);
        int nbm = Bsz / 128, nbn = (C + 127) / 128;
        gemm_fused<<<nbm * nbn, 256, 0, stream>>>(xn, w, out, Bsz, C, D);
    } else {
        float* invx = (float*)d_ws;
        float* invw = invx + Bsz;
        rownorm_inv<<<(Bsz + 3) / 4, 256, 0, stream>>>(x, invx, Bsz);
        rownorm_inv<<<(C + 3) / 4, 256, 0, stream>>>(w, invw, C);
        dim3 g((C + 255) / 256, Bsz);
        naive_gemm<<<g, 256, 0, stream>>>(x, w, invx, invw, out, Bsz, C);
    }
    fixup_kernel<<<(Bsz + 255) / 256, 256, 0, stream>>>(label, out, Bsz, C);
}

// Round 4
// 562.827 us; speedup vs baseline: 1.0383x; 1.0383x over previous
//
#include <hip/hip_runtime.h>
#include <hip/hip_bf16.h>
#include <cstdint>
#include <cstddef>

// ArcFace FC: out[i][j] = S * (j==label[i] ? phi(cos_ij) : cos_ij)
// cos = normalize(x) @ normalize(W)^T,  B=512, D=512, C=100000
//
// v5: barrier-free, wave-private-LDS fused GEMM.
//  - 64-thread workgroups: ONE wave owns a 64x64 tile; all LDS is wave-
//    private, so write->read ordering is per-wave lgkmcnt (compiler-counted)
//    and NO __syncthreads exists anywhere -> no vmcnt(0) drain (v2's stall).
//  - Loads are line-coalesced (v4's 16-line/instr fragment loads were
//    TA-bound at 6% MfmaUtil): W fp32 read as 8 lanes covering one full
//    128B line; A bf16 as 4 lanes per 64B row-chunk. Staged into the
//    v2-proven XOR-swizzled LDS layout (conflict-free ds_read_b128 frags).
//  - 2x unrolled K-loop with two named register sets: loads for step t+1
//    issue before processing step t (compiler emits counted vmcnt).
//  - W normalization fused: ss from fp32 regs, epilogue scale via sInv[64].
//  - XCD-chunked remap: 8 bm-blocks sharing a W tile co-run on one XCD.

#define SSCALE 30.0f
#define COSM_  0.8775825618903728f
#define SINM_  0.4794255386042030f
#define TH_    (-0.8775825618903728f)
#define MM_    0.2397127693021015f
#define EPS_   1e-12f

typedef unsigned short ushort_t;
typedef __attribute__((ext_vector_type(8))) short bf16x8;
typedef __attribute__((ext_vector_type(4))) short bf16x4;
typedef __attribute__((ext_vector_type(16))) float f32x16;

__device__ inline ushort_t f2bf(float f) {
    union { float f; unsigned u; } x; x.f = f;
    unsigned r = (x.u + 0x7fffu + ((x.u >> 16) & 1u)) >> 16;
    return (ushort_t)r;
}

__device__ inline ushort_t bfbits(float f) {
    union { __hip_bfloat16 h; ushort_t u; } c;
    c.h = __float2bfloat16(f);
    return c.u;
}

// ---------------- normalize x rows (D=512) fp32 -> bf16 (tiny: 512 rows) ----
__global__ __launch_bounds__(256) void norm_rows_bf16(const float* __restrict__ src,
                                                      ushort_t* __restrict__ dst,
                                                      int nrows) {
    int row = blockIdx.x * 4 + (threadIdx.x >> 6);
    if (row >= nrows) return;
    int lane = threadIdx.x & 63;
    const float* s = src + (size_t)row * 512;
    float4 a = ((const float4*)s)[lane];
    float4 b = ((const float4*)s)[lane + 64];
    float ss = a.x*a.x + a.y*a.y + a.z*a.z + a.w*a.w
             + b.x*b.x + b.y*b.y + b.z*b.z + b.w*b.w;
    #pragma unroll
    for (int off = 32; off > 0; off >>= 1) ss += __shfl_down(ss, off, 64);
    ss = __shfl(ss, 0, 64);
    float inv = 1.0f / fmaxf(sqrtf(ss), EPS_);
    ushort_t* d = dst + (size_t)row * 512;
    union { ushort_t u[4]; uint2 v; } oa, ob;
    oa.u[0] = f2bf(a.x * inv); oa.u[1] = f2bf(a.y * inv);
    oa.u[2] = f2bf(a.z * inv); oa.u[3] = f2bf(a.w * inv);
    ob.u[0] = f2bf(b.x * inv); ob.u[1] = f2bf(b.y * inv);
    ob.u[2] = f2bf(b.z * inv); ob.u[3] = f2bf(b.w * inv);
    ((uint2*)d)[lane]      = oa.v;
    ((uint2*)d)[lane + 64] = ob.v;
}

// ---------------- barrier-free wave-private fused GEMM ----------------------
// out[M,N] = S * A[M,K] @ (W[N,K] * invw[N])^T,  A already normalized bf16.
// One 64-lane wave per block computes 64x64 via 2x2 of mfma_f32_32x32x16.
// LDS (wave-private): lA[64][32], lB[64][32] bf16, chunk c (16B) of row r
// stored at slot (c ^ ((r>>1)&3)) -> conflict-free frag ds_read_b128.
__global__ __launch_bounds__(64, 2) void gemm_fused(const ushort_t* __restrict__ A,
                                                    const float* __restrict__ W,
                                                    float* __restrict__ out,
                                                    int M, int N, int K) {
    __shared__ ushort_t lA[64 * 32];     // 4 KB
    __shared__ ushort_t lB[64 * 32];     // 4 KB
    __shared__ float sInv[64];
    int lane = threadIdx.x;              // 0..63, one wave
    int half = lane >> 5, n5 = lane & 31;

    // XCD-chunked bijective remap (bm fastest within an XCD's chunk)
    int nwg = gridDim.x;
    int nbm = M >> 6;
    int q = nwg >> 3, r = nwg & 7;
    int xcd = blockIdx.x & 7, pos = blockIdx.x >> 3;
    int logical = (xcd < r ? xcd * (q + 1) : r * (q + 1) + (xcd - r) * q) + pos;
    int bm = logical % nbm;
    int bn = logical / nbm;

    f32x16 acc[2][2];
    #pragma unroll
    for (int mt = 0; mt < 2; mt++)
        #pragma unroll
        for (int nt = 0; nt < 2; nt++)
            #pragma unroll
            for (int r2 = 0; r2 < 16; r2++)
                acc[mt][nt][r2] = 0.f;

    // A staging: sweep j=0..3, lane covers row 16j+(lane>>2), chunk lane&3
    int arowl = lane >> 2;
    int afc   = lane & 3;
    const ushort_t* agA = A + (size_t)(bm * 64 + arowl) * K + afc * 8;
    int aidx = arowl * 32 + (afc ^ ((arowl >> 1) & 3)) * 8;    // + j*512

    // W staging: sweep s=0..7, lane covers row 8s+(lane>>3), float4 lane&7
    // (8 lanes span one full 128B line -> fully coalesced)
    int wrowl = lane >> 3;
    int wf4   = lane & 7;
    const float* pw[8];
    #pragma unroll
    for (int s = 0; s < 8; s++) {
        int rg = bn * 64 + 8 * s + wrowl;
        if (rg > N - 1) rg = N - 1;
        pw[s] = W + (size_t)rg * K + 4 * wf4;
    }
    int widx = wrowl * 32 + ((wf4 >> 1) ^ ((wrowl >> 1) & 3)) * 8 + (wf4 & 1) * 4; // + s*256

    // fragment reads (v2-proven): row n5 (+32), chunk (ks*2+half) ^ swz
    int sw  = (n5 >> 1) & 3;
    int cs0 = (half ^ sw) * 8;
    int cs1 = ((2 ^ half ^ sw)) * 8;
    const ushort_t* pArow = lA + n5 * 32;
    const ushort_t* pBrow = lB + n5 * 32;

    float ss[8];
    #pragma unroll
    for (int s = 0; s < 8; s++) ss[s] = 0.f;

    const int NT = K >> 5;

#define LOADSET(Ar, Wr, kt) do { int k0_ = (kt) << 5;                          \
    _Pragma("unroll")                                                          \
    for (int j_ = 0; j_ < 4; j_++)                                             \
        Ar[j_] = *(const bf16x8*)(agA + (size_t)j_ * 16 * K + k0_);            \
    _Pragma("unroll")                                                          \
    for (int s_ = 0; s_ < 8; s_++)                                             \
        Wr[s_] = *(const float4*)(pw[s_] + k0_);                               \
} while (0)

#define PROCSET(Ar, Wr) do {                                                   \
    _Pragma("unroll")                                                          \
    for (int s_ = 0; s_ < 8; s_++) {                                           \
        float4 v_ = Wr[s_];                                                    \
        ss[s_] += v_.x*v_.x + v_.y*v_.y + v_.z*v_.z + v_.w*v_.w;               \
        bf16x4 wb_;                                                            \
        wb_[0] = (short)bfbits(v_.x); wb_[1] = (short)bfbits(v_.y);            \
        wb_[2] = (short)bfbits(v_.z); wb_[3] = (short)bfbits(v_.w);            \
        *(bf16x4*)(lB + s_ * 256 + widx) = wb_;                                \
    }                                                                          \
    _Pragma("unroll")                                                          \
    for (int j_ = 0; j_ < 4; j_++)                                             \
        *(bf16x8*)(lA + j_ * 512 + aidx) = Ar[j_];                             \
    {                                                                          \
        bf16x8 af0_[2], af1_[2], bf0_[2], bf1_[2];                             \
        _Pragma("unroll")                                                      \
        for (int mt_ = 0; mt_ < 2; mt_++) {                                    \
            af0_[mt_] = *(const bf16x8*)(pArow + mt_ * 1024 + cs0);            \
            af1_[mt_] = *(const bf16x8*)(pArow + mt_ * 1024 + cs1);            \
        }                                                                      \
        _Pragma("unroll")                                                      \
        for (int nt_ = 0; nt_ < 2; nt_++) {                                    \
            bf0_[nt_] = *(const bf16x8*)(pBrow + nt_ * 1024 + cs0);            \
            bf1_[nt_] = *(const bf16x8*)(pBrow + nt_ * 1024 + cs1);            \
        }                                                                      \
        _Pragma("unroll")                                                      \
        for (int mt_ = 0; mt_ < 2; mt_++)                                      \
            _Pragma("unroll")                                                  \
            for (int nt_ = 0; nt_ < 2; nt_++) {                                \
                acc[mt_][nt_] = __builtin_amdgcn_mfma_f32_32x32x16_bf16(       \
                    af0_[mt_], bf0_[nt_], acc[mt_][nt_], 0, 0, 0);             \
                acc[mt_][nt_] = __builtin_amdgcn_mfma_f32_32x32x16_bf16(       \
                    af1_[mt_], bf1_[nt_], acc[mt_][nt_], 0, 0, 0);             \
            }                                                                  \
    }                                                                          \
} while (0)

    bf16x8 A0[4], A1[4];
    float4 W0[8], W1[8];
    LOADSET(A0, W0, 0);
    for (int t = 0; t < NT; t += 2) {
        if (t + 1 < NT) LOADSET(A1, W1, t + 1);
        PROCSET(A0, W0);
        if (t + 2 < NT) LOADSET(A0, W0, t + 2);
        if (t + 1 < NT) PROCSET(A1, W1);
    }
#undef LOADSET
#undef PROCSET

    // 1/||w||: ss[s] is the (wf4)-quarter partial of row 8s+wrowl; reduce
    // across the 8-lane group (xor 1,2,4), publish to wave-private sInv.
    #pragma unroll
    for (int s = 0; s < 8; s++) {
        float t = ss[s];
        t += __shfl_xor(t, 1, 64);
        t += __shfl_xor(t, 2, 64);
        t += __shfl_xor(t, 4, 64);
        if (wf4 == 0) sInv[8 * s + wrowl] = SSCALE / fmaxf(sqrtf(t), EPS_);
    }
    // same wave wrote sInv -> lgkmcnt ordering suffices, no barrier

    // epilogue: 32x32 C/D layout col = lane&31, row = (reg&3)+8*(reg>>2)+4*half
    int row0 = bm * 64 + 4 * half;
    #pragma unroll
    for (int nt = 0; nt < 2; nt++) {
        int cl = n5 + nt * 32;
        int c  = bn * 64 + cl;
        if (c < N) {
            float sc = sInv[cl];
            #pragma unroll
            for (int mt = 0; mt < 2; mt++) {
                #pragma unroll
                for (int r2 = 0; r2 < 16; r2++) {
                    int row = row0 + mt * 32 + (r2 & 3) + 8 * (r2 >> 2);
                    __builtin_nontemporal_store(acc[mt][nt][r2] * sc,
                                                &out[(size_t)row * N + c]);
                }
            }
        }
    }
}

// ---------------- fixup: apply arcface margin at (i, label[i]) ---------------
__global__ void fixup_kernel(const int* __restrict__ label, float* __restrict__ out,
                             int Bsz, int C) {
    int i = blockIdx.x * blockDim.x + threadIdx.x;
    if (i >= Bsz) return;
    int j = label[i];
    size_t idx = (size_t)i * C + j;
    float cosv = out[idx] * (1.0f / SSCALE);
    float sinv = sqrtf(fmaxf(0.f, 1.f - cosv * cosv));
    float phi = cosv * COSM_ - sinv * SINM_;
    if (!(cosv > TH_)) phi = cosv - MM_;
    out[idx] = phi * SSCALE;
}

// ---------------- fallback path (workspace too small / odd shapes) ----------
__global__ __launch_bounds__(256) void rownorm_inv(const float* __restrict__ in,
                                                   float* __restrict__ invn, int nrows) {
    int row = blockIdx.x * 4 + (threadIdx.x >> 6);
    if (row >= nrows) return;
    int lane = threadIdx.x & 63;
    const float4* p = (const float4*)(in + (size_t)row * 512);
    float4 a = p[lane];
    float4 b = p[lane + 64];
    float ss = a.x*a.x + a.y*a.y + a.z*a.z + a.w*a.w
             + b.x*b.x + b.y*b.y + b.z*b.z + b.w*b.w;
    #pragma unroll
    for (int off = 32; off > 0; off >>= 1) ss += __shfl_down(ss, off, 64);
    if (lane == 0) invn[row] = 1.0f / fmaxf(sqrtf(ss), EPS_);
}

__global__ __launch_bounds__(256) void naive_gemm(const float* __restrict__ x,
                                                  const float* __restrict__ w,
                                                  const float* __restrict__ invx,
                                                  const float* __restrict__ invw,
                                                  float* __restrict__ out, int Bsz, int C) {
    __shared__ float xs[512];
    int i = blockIdx.y;
    int j = blockIdx.x * 256 + threadIdx.x;
    for (int k = threadIdx.x; k < 512; k += 256) xs[k] = x[(size_t)i * 512 + k];
    __syncthreads();
    if (j >= C) return;
    const float* wr = w + (size_t)j * 512;
    float acc = 0.f;
    for (int k = 0; k < 512; k++) acc += xs[k] * wr[k];
    out[(size_t)i * C + j] = acc * invx[i] * invw[j] * SSCALE;
}

extern "C" void kernel_launch(void* const* d_in, const int* in_sizes, int n_in,
                              void* d_out, int out_size, void* d_ws, size_t ws_size,
                              hipStream_t stream) {
    const float* x = (const float*)d_in[0];
    const float* w = (const float*)d_in[1];
    const int* label = (const int*)d_in[2];
    float* out = (float*)d_out;

    const int Bsz = in_sizes[2];            // 512
    const int D   = 512;
    const int C   = in_sizes[1] / D;        // 100000

    size_t need = (size_t)Bsz * D * sizeof(ushort_t);   // xn only: 512 KB
    if (ws_size >= need && (Bsz % 64) == 0 && (D % 64) == 0) {
        ushort_t* xn = (ushort_t*)d_ws;
        norm_rows_bf16<<<(Bsz + 3) / 4, 256, 0, stream>>>(x, xn, Bsz);
        int nbm = Bsz / 64, nbn = (C + 63) / 64;
        gemm_fused<<<nbm * nbn, 64, 0, stream>>>(xn, w, out, Bsz, C, D);
    } else {
        float* invx = (float*)d_ws;
        float* invw = invx + Bsz;
        rownorm_inv<<<(Bsz + 3) / 4, 256, 0, stream>>>(x, invx, Bsz);
        rownorm_inv<<<(C + 3) / 4, 256, 0, stream>>>(w, invw, C);
        dim3 g((C + 255) / 256, Bsz);
        naive_gemm<<<g, 256, 0, stream>>>(x, w, invx, invw, out, Bsz, C);
    }
    fixup_kernel<<<(Bsz + 255) / 256, 256, 0, stream>>>(label, out, Bsz, C);
}

// Round 5
// 406.645 us; speedup vs baseline: 1.4371x; 1.3841x over previous
//
#include <hip/hip_runtime.h>
#include <hip/hip_bf16.h>
#include <cstdint>
#include <cstddef>

// ArcFace FC: out[i][j] = S * (j==label[i] ? phi(cos_ij) : cos_ij)
// cos = normalize(x) @ normalize(W)^T,  B=512, D=512, C=100000
//
// v6: W read ONCE as fp32 via global_load_lds (the only staging path that
// ever performed: R0's gemm ~100us; all reg-staged variants 171-356us).
// Conversion fp32->bf16 happens AFTER ds_read, per fragment (cvt_pk, cheap).
// ||w|| from a tiny invw-only pre-pass (fused with x-norm); epilogue scales
// by invw[c]*S (exact post-dot scaling). Single-barrier double-buffered
// K-loop: STAGE(t+1) in flight across the whole compute(t) phase.
// B-side LDS uses the guide-proven 8-slot XOR swizzle (c ^= row&7) over
// 128B fp32 rows -> all 32 banks (the old 4-slot swizzle left 6.4M conflicts).

#define SSCALE 30.0f
#define COSM_  0.8775825618903728f
#define SINM_  0.4794255386042030f
#define TH_    (-0.8775825618903728f)
#define MM_    0.2397127693021015f
#define EPS_   1e-12f

typedef unsigned short ushort_t;
typedef __attribute__((ext_vector_type(8))) short bf16x8;
typedef __attribute__((ext_vector_type(16))) float f32x16;

__device__ inline ushort_t f2bf(float f) {
    union { float f; unsigned u; } x; x.f = f;
    unsigned r = (x.u + 0x7fffu + ((x.u >> 16) & 1u)) >> 16;
    return (ushort_t)r;
}

__device__ inline ushort_t bfbits(float f) {
    union { __hip_bfloat16 h; ushort_t u; } c;
    c.h = __float2bfloat16(f);
    return c.u;
}

__device__ inline bf16x8 cvt8(float4 a, float4 b) {
    bf16x8 r;
    r[0] = (short)bfbits(a.x); r[1] = (short)bfbits(a.y);
    r[2] = (short)bfbits(a.z); r[3] = (short)bfbits(a.w);
    r[4] = (short)bfbits(b.x); r[5] = (short)bfbits(b.y);
    r[6] = (short)bfbits(b.z); r[7] = (short)bfbits(b.w);
    return r;
}

// ---- pre-pass: rows<C -> invw[row] only; rows>=C -> x normalized to bf16 ----
__global__ __launch_bounds__(256) void norm_inv_all(const float* __restrict__ x,
                                                    const float* __restrict__ w,
                                                    ushort_t* __restrict__ xn,
                                                    float* __restrict__ invw,
                                                    int C, int Bsz) {
    int rowg = blockIdx.x * 4 + (threadIdx.x >> 6);
    if (rowg >= C + Bsz) return;
    int lane = threadIdx.x & 63;
    const float* src = (rowg < C) ? w + (size_t)rowg * 512
                                  : x + (size_t)(rowg - C) * 512;
    float4 a = ((const float4*)src)[lane];
    float4 b = ((const float4*)src)[lane + 64];
    float ss = a.x*a.x + a.y*a.y + a.z*a.z + a.w*a.w
             + b.x*b.x + b.y*b.y + b.z*b.z + b.w*b.w;
    #pragma unroll
    for (int off = 32; off > 0; off >>= 1) ss += __shfl_down(ss, off, 64);
    if (rowg < C) {
        if (lane == 0) invw[rowg] = 1.0f / fmaxf(sqrtf(ss), EPS_);
        return;
    }
    ss = __shfl(ss, 0, 64);
    float inv = 1.0f / fmaxf(sqrtf(ss), EPS_);
    ushort_t* d = xn + (size_t)(rowg - C) * 512;
    union { ushort_t u[4]; uint2 v; } oa, ob;
    oa.u[0] = f2bf(a.x * inv); oa.u[1] = f2bf(a.y * inv);
    oa.u[2] = f2bf(a.z * inv); oa.u[3] = f2bf(a.w * inv);
    ob.u[0] = f2bf(b.x * inv); ob.u[1] = f2bf(b.y * inv);
    ob.u[2] = f2bf(b.z * inv); ob.u[3] = f2bf(b.w * inv);
    ((uint2*)d)[lane]      = oa.v;
    ((uint2*)d)[lane + 64] = ob.v;
}

// ---------------- fused GEMM: out = S * A @ (W * invw)^T --------------------
// A[M,K] normalized bf16; W[N,K] raw fp32; 128x128 tile, BK=32, 4 waves,
// each 64x64 via 2x2 of mfma_f32_32x32x16_bf16 (2 k-steps of 16).
// lA (bf16): 128 rows x 4 chunks(16B), chunk ^= (row>>1)&3 (v2 pattern).
// lB (fp32): 128 rows x 8 chunks(16B), chunk ^= row&7 (G4 pattern, 32 banks).
// Both staged by global_load_lds (linear dest; source picks realize swizzle).
__global__ __launch_bounds__(256) void gemm_fused(const ushort_t* __restrict__ A,
                                                  const float* __restrict__ W,
                                                  const float* __restrict__ invw,
                                                  float* __restrict__ out,
                                                  int M, int N, int K) {
    __shared__ ushort_t lA[2][128 * 32];   // 2 x 8 KB
    __shared__ float    lB[2][128 * 32];   // 2 x 16 KB
    int tid  = threadIdx.x;
    int wave = tid >> 6, lane = tid & 63;
    int half = lane >> 5, n5 = lane & 31;

    // XCD-chunked bijective remap (bm fastest within an XCD chunk)
    int nwg = gridDim.x;
    int nbm = M >> 7;
    int q = nwg >> 3, r = nwg & 7;
    int xcd = blockIdx.x & 7, pos = blockIdx.x >> 3;
    int logical = (xcd < r ? xcd * (q + 1) : r * (q + 1) + (xcd - r) * q) + pos;
    int bm = logical % nbm;
    int bn = logical / nbm;

    f32x16 acc[2][2];
    #pragma unroll
    for (int mt = 0; mt < 2; mt++)
        #pragma unroll
        for (int nt = 0; nt < 2; nt++)
            #pragma unroll
            for (int r2 = 0; r2 < 16; r2++)
                acc[mt][nt][r2] = 0.f;

    // A staging (2 x glds16): slot s = tid + 256*i -> row s>>2, stored chunk
    // s&3; source chunk = (s&3) ^ ((row>>1)&3) = (tid&3) ^ ((tid>>3)&3).
    int arow = tid >> 2;
    int ac0  = (tid & 3) ^ ((tid >> 3) & 3);
    const ushort_t* ag0 = A + (size_t)(bm * 128 + arow) * K + ac0 * 8;
    const ushort_t* ag1 = ag0 + (size_t)64 * K;

    // W staging (4 x glds16): slot s = tid + 256*i -> row s>>3 = (tid>>3)+32i,
    // stored chunk s&7; source chunk = (s&7) ^ (row&7) = (tid&7) ^ ((tid>>3)&7).
    int wrow = tid >> 3;
    int wc   = (tid & 7) ^ (wrow & 7);
    const float* wg[4];
    #pragma unroll
    for (int i = 0; i < 4; i++) {
        int rg = bn * 128 + wrow + 32 * i;
        if (rg > N - 1) rg = N - 1;
        wg[i] = W + (size_t)rg * K + wc * 4;
    }

    // fragment read addressing
    int swA  = (n5 >> 1) & 3;
    int ca0  = (half ^ swA) * 8;               // ks=0 chunk (ushorts)
    int ca1  = ((2 ^ half) ^ swA) * 8;         // ks=1
    int baseA = ((wave >> 1) * 64 + n5) * 32;  // ushort idx
    int r8   = n5 & 7;
    int baseB = ((wave & 1) * 64 + n5) * 32;   // float idx (row = 32 floats)

#define GLDS(gp, lp) __builtin_amdgcn_global_load_lds(                         \
        (const __attribute__((address_space(1))) void*)(gp),                   \
        (__attribute__((address_space(3))) void*)(lp), 16, 0, 0)

#define STAGE(b, k0) do {                                                      \
    GLDS(ag0 + (k0), &lA[b][wave * 512]);                                      \
    GLDS(ag1 + (k0), &lA[b][2048 + wave * 512]);                               \
    GLDS(wg[0] + (k0), &lB[b][wave * 256]);                                    \
    GLDS(wg[1] + (k0), &lB[b][1024 + wave * 256]);                             \
    GLDS(wg[2] + (k0), &lB[b][2048 + wave * 256]);                             \
    GLDS(wg[3] + (k0), &lB[b][3072 + wave * 256]);                             \
} while (0)

    const int NT = K >> 5;
    int cur = 0;
    STAGE(0, 0);
    __syncthreads();

    for (int t = 0; t < NT; ++t) {
        if (t + 1 < NT) STAGE(cur ^ 1, (t + 1) << 5);

        bf16x8 af[2][2], bfr[2][2];
        #pragma unroll
        for (int mt = 0; mt < 2; mt++) {
            af[mt][0] = *(const bf16x8*)&lA[cur][baseA + mt * 1024 + ca0];
            af[mt][1] = *(const bf16x8*)&lA[cur][baseA + mt * 1024 + ca1];
        }
        #pragma unroll
        for (int nt = 0; nt < 2; nt++) {
            #pragma unroll
            for (int ks = 0; ks < 2; ks++) {
                int p0 = (ks * 4 + half * 2) ^ r8;
                float4 f0 = *(const float4*)&lB[cur][baseB + nt * 1024 + (p0 << 2)];
                float4 f1 = *(const float4*)&lB[cur][baseB + nt * 1024 + ((p0 ^ 1) << 2)];
                bfr[nt][ks] = cvt8(f0, f1);
            }
        }
        #pragma unroll
        for (int ks = 0; ks < 2; ks++)
            #pragma unroll
            for (int mt = 0; mt < 2; mt++)
                #pragma unroll
                for (int nt = 0; nt < 2; nt++)
                    acc[mt][nt] = __builtin_amdgcn_mfma_f32_32x32x16_bf16(
                        af[mt][ks], bfr[nt][ks], acc[mt][nt], 0, 0, 0);

        if (t + 1 < NT) { __syncthreads(); cur ^= 1; }
    }
#undef STAGE
#undef GLDS

    // epilogue: 32x32 C/D layout col = lane&31, row = (reg&3)+8*(reg>>2)+4*half
    int row0 = bm * 128 + (wave >> 1) * 64 + 4 * half;
    int col0 = bn * 128 + (wave & 1) * 64 + n5;
    #pragma unroll
    for (int nt = 0; nt < 2; nt++) {
        int c = col0 + nt * 32;
        if (c < N) {
            float sc = invw[c] * SSCALE;
            #pragma unroll
            for (int mt = 0; mt < 2; mt++) {
                #pragma unroll
                for (int r2 = 0; r2 < 16; r2++) {
                    int row = row0 + mt * 32 + (r2 & 3) + 8 * (r2 >> 2);
                    __builtin_nontemporal_store(acc[mt][nt][r2] * sc,
                                                &out[(size_t)row * N + c]);
                }
            }
        }
    }
}

// ---------------- fixup: apply arcface margin at (i, label[i]) ---------------
__global__ void fixup_kernel(const int* __restrict__ label, float* __restrict__ out,
                             int Bsz, int C) {
    int i = blockIdx.x * blockDim.x + threadIdx.x;
    if (i >= Bsz) return;
    int j = label[i];
    size_t idx = (size_t)i * C + j;
    float cosv = out[idx] * (1.0f / SSCALE);
    float sinv = sqrtf(fmaxf(0.f, 1.f - cosv * cosv));
    float phi = cosv * COSM_ - sinv * SINM_;
    if (!(cosv > TH_)) phi = cosv - MM_;
    out[idx] = phi * SSCALE;
}

// ---------------- fallback path (workspace too small / odd shapes) ----------
__global__ __launch_bounds__(256) void rownorm_inv(const float* __restrict__ in,
                                                   float* __restrict__ invn, int nrows) {
    int row = blockIdx.x * 4 + (threadIdx.x >> 6);
    if (row >= nrows) return;
    int lane = threadIdx.x & 63;
    const float4* p = (const float4*)(in + (size_t)row * 512);
    float4 a = p[lane];
    float4 b = p[lane + 64];
    float ss = a.x*a.x + a.y*a.y + a.z*a.z + a.w*a.w
             + b.x*b.x + b.y*b.y + b.z*b.z + b.w*b.w;
    #pragma unroll
    for (int off = 32; off > 0; off >>= 1) ss += __shfl_down(ss, off, 64);
    if (lane == 0) invn[row] = 1.0f / fmaxf(sqrtf(ss), EPS_);
}

__global__ __launch_bounds__(256) void naive_gemm(const float* __restrict__ x,
                                                  const float* __restrict__ w,
                                                  const float* __restrict__ invx,
                                                  const float* __restrict__ invw,
                                                  float* __restrict__ out, int Bsz, int C) {
    __shared__ float xs[512];
    int i = blockIdx.y;
    int j = blockIdx.x * 256 + threadIdx.x;
    for (int k = threadIdx.x; k < 512; k += 256) xs[k] = x[(size_t)i * 512 + k];
    __syncthreads();
    if (j >= C) return;
    const float* wr = w + (size_t)j * 512;
    float acc = 0.f;
    for (int k = 0; k < 512; k++) acc += xs[k] * wr[k];
    out[(size_t)i * C + j] = acc * invx[i] * invw[j] * SSCALE;
}

extern "C" void kernel_launch(void* const* d_in, const int* in_sizes, int n_in,
                              void* d_out, int out_size, void* d_ws, size_t ws_size,
                              hipStream_t stream) {
    const float* x = (const float*)d_in[0];
    const float* w = (const float*)d_in[1];
    const int* label = (const int*)d_in[2];
    float* out = (float*)d_out;

    const int Bsz = in_sizes[2];            // 512
    const int D   = 512;
    const int C   = in_sizes[1] / D;        // 100000

    size_t need = (size_t)Bsz * D * sizeof(ushort_t) + (size_t)C * sizeof(float);
    if (ws_size >= need && (Bsz % 128) == 0) {
        ushort_t* xn = (ushort_t*)d_ws;
        float* invw = (float*)(xn + (size_t)Bsz * D);
        norm_inv_all<<<(C + Bsz + 3) / 4, 256, 0, stream>>>(x, w, xn, invw, C, Bsz);
        int nbm = Bsz / 128, nbn = (C + 127) / 128;
        gemm_fused<<<nbm * nbn, 256, 0, stream>>>(xn, w, invw, out, Bsz, C, D);
    } else {
        float* invx = (float*)d_ws;
        float* invw = invx + Bsz;
        rownorm_inv<<<(Bsz + 3) / 4, 256, 0, stream>>>(x, invx, Bsz);
        rownorm_inv<<<(C + 3) / 4, 256, 0, stream>>>(w, invw, C);
        dim3 g((C + 255) / 256, Bsz);
        naive_gemm<<<g, 256, 0, stream>>>(x, w, invx, invw, out, Bsz, C);
    }
    fixup_kernel<<<(Bsz + 255) / 256, 256, 0, stream>>>(label, out, Bsz, C);
}